// Round 2
// baseline (51.225 us; speedup 1.0000x reference)
//
#include <hip/hip_runtime.h>
#include <math.h>

#define NPART 8
#define NN    128   // neighbors per batch
#define B_UNITS 512 // float4 units per batch: 128*8*2/4

// One block per batch element b, 128 threads (2 waves).
// Stage: 8KB of nei_trajs[b] -> LDS via global_load_lds (coalesced, 16B/lane),
//        with the global SOURCE pre-swizzled so a linear LDS write + swizzled
//        ds_read_b128 gives each thread its neighbor's 64B conflict-free.
// Phase 1: thread n computes velocity/distance/direction + validity for
//          neighbor n, LDS-atomic accumulates into 8 angle bins.
// Phase 2: 24 threads finalize social_circle = sum/(cnt+eps), write output 1.
// Phase 3: thread c computes f_sc[b,p,c] = relu(sc[p,:] . W[:,c] + b[c]).
__global__ __launch_bounds__(128) void sc_kernel(
    const float* __restrict__ nei,   // (B, 128, 8, 2) f32
    const float* __restrict__ W,     // (3, 128) f32
    const float* __restrict__ bce,   // (128,) f32
    float* __restrict__ fsc,         // (B, 8, 128) f32
    float* __restrict__ scout,       // (B, 8, 3) f32
    int Btot)
{
    const int b    = blockIdx.x;
    if (b >= Btot) return;
    const int tid  = threadIdx.x;
    const int lane = tid & 63;
    const int wv   = tid >> 6;

    __shared__ float4 st[B_UNITS];      // 8 KB staging
    __shared__ float  s_sum[NPART * 3];
    __shared__ float  s_cnt[NPART];
    __shared__ float  s_sc[NPART * 3];

    // Hoist the (L2-hot) weight/bias loads above the staging barrier.
    float w0 = W[tid], w1 = W[NN + tid], w2 = W[2 * NN + tid];
    float bb = bce[tid];

    const float4* src = reinterpret_cast<const float4*>(nei) + (size_t)b * B_UNITS;

    // ---- Stage: LDS[u] = src[inv_s(u)], so LDS[s(j)] = src[j] ----
    // s(j) = j ^ ((j>>2)&7); inverse: j2=u2^u4, j1=u1^u3, j0=u0^j2.
    #pragma unroll
    for (int k = 0; k < 4; ++k) {
        int u  = k * 128 + wv * 64 + lane;       // LDS unit this lane fills
        int b2 = ((u >> 2) ^ (u >> 4)) & 1;
        int b1 = ((u >> 1) ^ (u >> 3)) & 1;
        int b0 = (u ^ b2) & 1;
        int j  = (u & ~7) | (b2 << 2) | (b1 << 1) | b0;
        __builtin_amdgcn_global_load_lds(
            (const __attribute__((address_space(1))) void*)(src + j),
            (__attribute__((address_space(3))) void*)(st + k * 128 + wv * 64),
            16, 0, 0);
    }

    if (tid < NPART * 3) s_sum[tid] = 0.0f;
    if (tid < NPART)     s_cnt[tid] = 0.0f;
    asm volatile("s_waitcnt vmcnt(0)");
    __syncthreads();

    // ---- Phase 1: read neighbor tid's 4 float4s (swizzled, conflict-free) ----
    float4 a, c, d, e;
    {
        int m = tid & 7;
        a = st[(tid * 4 + 0) ^ m];
        c = st[(tid * 4 + 1) ^ m];
        d = st[(tid * 4 + 2) ^ m];
        e = st[(tid * 4 + 3) ^ m];
    }

    float total = (((a.x + a.y) + (a.z + a.w)) + ((c.x + c.y) + (c.z + c.w)))
                + (((d.x + d.y) + (d.z + d.w)) + ((e.x + e.y) + (e.z + e.w)));

    float px = e.z, py = e.w;            // last position (t7)
    float vx = px - a.x, vy = py - a.y;  // last - first
    float fvel  = sqrtf(vx * vx + vy * vy);
    float fdist = sqrtf(px * px + py * py);

    float fdir = atan2f(px, py);
    if (fdir < 0.0f) fdir += 6.2831853071795864769f;

    const float STEP = (float)(6.283185307179586 / 8.0);
    int idx = (int)(fdir / STEP);

    if (total != 0.0f && idx >= 0 && idx < NPART) {
        atomicAdd(&s_sum[idx * 3 + 0], fvel);
        atomicAdd(&s_sum[idx * 3 + 1], fdist);
        atomicAdd(&s_sum[idx * 3 + 2], fdir);
        atomicAdd(&s_cnt[idx], 1.0f);
    }
    __syncthreads();

    // ---- Phase 2: social_circle finalize + write output 1 ----
    if (tid < NPART * 3) {
        float v = s_sum[tid] / (s_cnt[tid / 3] + 0.0001f);
        s_sc[tid] = v;
        scout[(size_t)b * (NPART * 3) + tid] = v;
    }
    __syncthreads();

    // ---- Phase 3: f_sc = relu(sc @ W + b), thread = output column ----
    float* o = fsc + (size_t)b * NPART * NN;
    #pragma unroll
    for (int p = 0; p < NPART; ++p) {
        float acc = bb;
        acc = fmaf(s_sc[p * 3 + 0], w0, acc);
        acc = fmaf(s_sc[p * 3 + 1], w1, acc);
        acc = fmaf(s_sc[p * 3 + 2], w2, acc);
        o[p * NN + tid] = fmaxf(acc, 0.0f);
    }
}

extern "C" void kernel_launch(void* const* d_in, const int* in_sizes, int n_in,
                              void* d_out, int out_size, void* d_ws, size_t ws_size,
                              hipStream_t stream) {
    // inputs: 0=trajs (UNUSED by reference), 1=nei_trajs, 2=W_ce, 3=b_ce
    const float* nei = (const float*)d_in[1];
    const float* W   = (const float*)d_in[2];
    const float* bce = (const float*)d_in[3];

    const int Btot = in_sizes[1] / (NN * 8 * 2);   // 16384

    // outputs concatenated: f_sc (B,8,128) then social_circle (B,8,3)
    float* fsc   = (float*)d_out;
    float* scout = fsc + (size_t)Btot * NPART * NN;

    sc_kernel<<<Btot, 128, 0, stream>>>(nei, W, bce, fsc, scout, Btot);
}

// Round 3
// 43.901 us; speedup vs baseline: 1.1668x; 1.1668x over previous
//
#include <hip/hip_runtime.h>
#include <math.h>

#define NPART 8
#define NN    128   // neighbors per batch
#define WPB   4     // waves (=batches) per block

// One WAVE per batch element. 256-thread blocks = 4 independent waves, each
// with a private LDS bin region -> no __syncthreads anywhere.
// Lane l handles neighbors l and l+64 (4+4 float4 loads, 8KB in flight/wave).
// Bins via per-wave LDS atomics; epilogue: lane l computes output columns
// 2l, 2l+1 for all 8 partitions (float2 stores, 512B/wave coalesced).
__global__ __launch_bounds__(256) void sc_kernel(
    const float* __restrict__ nei,   // (B, 128, 8, 2) f32
    const float* __restrict__ W,     // (3, 128) f32
    const float* __restrict__ bce,   // (128,) f32
    float* __restrict__ fsc,         // (B, 8, 128) f32
    float* __restrict__ scout,       // (B, 8, 3) f32
    int Btot)
{
    const int tid  = threadIdx.x;
    const int lane = tid & 63;
    const int wv   = tid >> 6;
    const int b    = blockIdx.x * WPB + wv;
    if (b >= Btot) return;

    __shared__ float s_sum[WPB][NPART * 3];
    __shared__ float s_cnt[WPB][NPART];
    __shared__ float s_sc[WPB][NPART * 3];

    // ---- issue all global loads first (overlap with LDS init) ----
    const float4* src = reinterpret_cast<const float4*>(nei) + (size_t)b * (NN * 4);
    // neighbor n0 = lane
    float4 a0 = src[lane * 4 + 0];
    float4 c0 = src[lane * 4 + 1];
    float4 d0 = src[lane * 4 + 2];
    float4 e0 = src[lane * 4 + 3];
    // neighbor n1 = lane + 64
    float4 a1 = src[256 + lane * 4 + 0];
    float4 c1 = src[256 + lane * 4 + 1];
    float4 d1 = src[256 + lane * 4 + 2];
    float4 e1 = src[256 + lane * 4 + 3];

    // weights for epilogue (L2-hot, overlap with the big loads)
    const int c0i = 2 * lane, c1i = 2 * lane + 1;
    float2 wr0 = *reinterpret_cast<const float2*>(W + 0 * NN + c0i);
    float2 wr1 = *reinterpret_cast<const float2*>(W + 1 * NN + c0i);
    float2 wr2 = *reinterpret_cast<const float2*>(W + 2 * NN + c0i);
    float2 bb  = *reinterpret_cast<const float2*>(bce + c0i);

    // per-wave LDS init (same wave that consumes -> in-order, no barrier)
    if (lane < NPART * 3) s_sum[wv][lane] = 0.0f;
    if (lane < NPART)     s_cnt[wv][lane] = 0.0f;
    __builtin_amdgcn_wave_barrier();

    const float TWOPI = 6.2831853071795864769f;
    const float STEP  = (float)(6.283185307179586 / 8.0);

    #pragma unroll
    for (int h = 0; h < 2; ++h) {
        float4 a = h ? a1 : a0;
        float4 c = h ? c1 : c0;
        float4 d = h ? d1 : d0;
        float4 e = h ? e1 : e0;

        float total = (((a.x + a.y) + (a.z + a.w)) + ((c.x + c.y) + (c.z + c.w)))
                    + (((d.x + d.y) + (d.z + d.w)) + ((e.x + e.y) + (e.z + e.w)));

        float px = e.z, py = e.w;            // last position (t7)
        float vx = px - a.x, vy = py - a.y;  // last - first
        float fvel  = sqrtf(vx * vx + vy * vy);
        float fdist = sqrtf(px * px + py * py);

        float fdir = atan2f(px, py);
        if (fdir < 0.0f) fdir += TWOPI;

        int idx = (int)(fdir / STEP);

        if (total != 0.0f && idx >= 0 && idx < NPART) {
            atomicAdd(&s_sum[wv][idx * 3 + 0], fvel);
            atomicAdd(&s_sum[wv][idx * 3 + 1], fdist);
            atomicAdd(&s_sum[wv][idx * 3 + 2], fdir);
            atomicAdd(&s_cnt[wv][idx], 1.0f);
        }
    }
    __builtin_amdgcn_wave_barrier();

    // ---- finalize social_circle (lanes 0..23), write output 1 ----
    if (lane < NPART * 3) {
        float v = s_sum[wv][lane] / (s_cnt[wv][lane / 3] + 0.0001f);
        s_sc[wv][lane] = v;
        scout[(size_t)b * (NPART * 3) + lane] = v;
    }
    __builtin_amdgcn_wave_barrier();

    // ---- epilogue: f_sc = relu(sc @ W + b); lane -> columns 2l, 2l+1 ----
    float* o = fsc + (size_t)b * NPART * NN;
    #pragma unroll
    for (int p = 0; p < NPART; ++p) {
        float sv = s_sc[wv][p * 3 + 0];   // broadcast reads (conflict-free)
        float sd = s_sc[wv][p * 3 + 1];
        float sr = s_sc[wv][p * 3 + 2];
        float2 acc;
        acc.x = fmaxf(fmaf(sv, wr0.x, fmaf(sd, wr1.x, fmaf(sr, wr2.x, bb.x))), 0.0f);
        acc.y = fmaxf(fmaf(sv, wr0.y, fmaf(sd, wr1.y, fmaf(sr, wr2.y, bb.y))), 0.0f);
        *reinterpret_cast<float2*>(o + p * NN + c0i) = acc;
    }
}

extern "C" void kernel_launch(void* const* d_in, const int* in_sizes, int n_in,
                              void* d_out, int out_size, void* d_ws, size_t ws_size,
                              hipStream_t stream) {
    // inputs: 0=trajs (UNUSED by reference), 1=nei_trajs, 2=W_ce, 3=b_ce
    const float* nei = (const float*)d_in[1];
    const float* W   = (const float*)d_in[2];
    const float* bce = (const float*)d_in[3];

    const int Btot = in_sizes[1] / (NN * 8 * 2);   // 16384

    // outputs concatenated: f_sc (B,8,128) then social_circle (B,8,3)
    float* fsc   = (float*)d_out;
    float* scout = fsc + (size_t)Btot * NPART * NN;

    const int nblk = (Btot + WPB - 1) / WPB;
    sc_kernel<<<nblk, 256, 0, stream>>>(nei, W, bce, fsc, scout, Btot);
}